// Round 16
// baseline (142.565 us; speedup 1.0000x reference)
//
#include <hip/hip_runtime.h>
#include <hip/hip_bf16.h>

#define N_NODES 1536
#define NF 64
#define NOUT 64
#define FIN 65

typedef __bf16 bf16x8 __attribute__((ext_vector_type(8)));
typedef float f32x4 __attribute__((ext_vector_type(4)));

// One block per i-row (grid 1536 = exactly 2 rounds at 3 blocks/CU).
//   D[o][j] = sum_k W[o][k] * |feat[j][k]-feat[i][k]|
// DRAM-locality experiment: wave wv owns j in [384*wv, 384*wv+384) and
// writes a strictly-ascending 96 KB contiguous stream (12 iters x 8 KB,
// no 384-KB jumps between chunks like every prior variant). Block-combined:
// 384 KB contiguous per block — the memset control's access shape, which
// sustains 6.8 TB/s vs our scattered pattern's 4.95. feat[j] fragments now
// load in-loop (L2-hot, 384 KB) software-pipelined one tile ahead with
// named A/B register sets; fi loads ONCE per block (single row). adj row
// (6 KB) staged to LDS at setup. Epilogue transposes each wave's 32j x 64o
// tile through wave-private XOR-swizzled LDS so stores are 1 KB
// lane-contiguous full lines. LDS 32+6=38 KB; x3 blocks = 114 KB/CU.
__global__ __launch_bounds__(256, 3)
void edge_gcn_mfma(const float* __restrict__ feat,
                   const float* __restrict__ adj,
                   const float* __restrict__ W,
                   const float* __restrict__ b,
                   float* __restrict__ out)
{
    const int tid  = threadIdx.x;
    const int lane = tid & 63;
    const int wv   = tid >> 6;          // wave 0..3
    const int l15  = lane & 15;
    const int lg   = lane >> 4;         // 0..3

    const int i  = blockIdx.x;
    const int jw = wv * 384;            // wave's contiguous j-range base

    __shared__ float lds[8192];         // 4 waves x 8 KB transpose buffers
    __shared__ float arow[N_NODES];     // adj row i (6 KB)
    float* const lbase = lds + wv * 2048;

    // ---- setup: adj row -> LDS (384 f32x4) ----
#pragma unroll
    for (int h = 0; h < 2; ++h) {
        const int idx = h * 256 + tid;
        if (idx < 384)
            *reinterpret_cast<f32x4*>(&arow[idx * 4]) =
                *reinterpret_cast<const f32x4*>(
                    &adj[(size_t)i * N_NODES + idx * 4]);
    }

    // ---- A fragments (W): once ----
    bf16x8 afrag[2][4];                 // [kk][mo]
#pragma unroll
    for (int kk = 0; kk < 2; ++kk)
#pragma unroll
        for (int mo = 0; mo < 4; ++mo) {
            const float* wp = W + (mo * 16 + l15) * FIN + kk * 32 + lg * 8;
#pragma unroll
            for (int e = 0; e < 8; ++e) afrag[kk][mo][e] = (__bf16)wp[e];
        }

    // ---- fi fragments: ONCE per block (single i-row), bf16 ----
    bf16x8 fib[2];
#pragma unroll
    for (int kk = 0; kk < 2; ++kk) {
        const float* fp = feat + (size_t)i * NF + kk * 32 + lg * 8;
#pragma unroll
        for (int e = 0; e < 8; ++e) fib[kk][e] = (__bf16)fp[e];
    }

    // ---- epilogue-B constants: o = l15*4 + r ----
    float wlB[4], bvB[4];
#pragma unroll
    for (int r = 0; r < 4; ++r) {
        wlB[r] = W[(l15 * 4 + r) * FIN + NF];
        bvB[r] = b[l15 * 4 + r];
    }

    __syncthreads();                    // arow ready; only barrier

    // ---- helpers ----
    auto load_fj = [&](bf16x8 fj[2][2], int it) {   // [n][kk]
#pragma unroll
        for (int n = 0; n < 2; ++n) {
            const float* fjrow =
                feat + (size_t)(jw + it * 32 + n * 16 + l15) * NF;
#pragma unroll
            for (int kk = 0; kk < 2; ++kk) {
                f32x4 lo = *reinterpret_cast<const f32x4*>(
                    fjrow + kk * 32 + lg * 8);
                f32x4 hi = *reinterpret_cast<const f32x4*>(
                    fjrow + kk * 32 + lg * 8 + 4);
#pragma unroll
                for (int e = 0; e < 4; ++e) {
                    fj[n][kk][e]     = (__bf16)lo[e];
                    fj[n][kk][e + 4] = (__bf16)hi[e];
                }
            }
        }
    };

    auto tile = [&](const bf16x8 fj[2][2], int it) {
        const int jt = jw + it * 32;    // tile j-base

        f32x4 acc[4][2];                // [mo][n]
#pragma unroll
        for (int mo = 0; mo < 4; ++mo)
#pragma unroll
            for (int n = 0; n < 2; ++n)
                acc[mo][n] = (f32x4){0.f, 0.f, 0.f, 0.f};

#pragma unroll
        for (int n = 0; n < 2; ++n)
#pragma unroll
            for (int kk = 0; kk < 2; ++kk) {
                bf16x8 bfrag;
#pragma unroll
                for (int e = 0; e < 8; ++e)
                    bfrag[e] = (__bf16)fabsf((float)fj[n][kk][e] -
                                             (float)fib[kk][e]);
#pragma unroll
                for (int mo = 0; mo < 4; ++mo)
                    acc[mo][n] = __builtin_amdgcn_mfma_f32_16x16x32_bf16(
                        afrag[kk][mo], bfrag, acc[mo][n], 0, 0, 0);
            }

        // epilogue A: raw acc -> transposed LDS tile
        // T[j(32)][o(64)], off = j*64 + (o ^ ((j&7)<<2))
#pragma unroll
        for (int n = 0; n < 2; ++n) {
            const int jrow = n * 16 + l15;
#pragma unroll
            for (int mo = 0; mo < 4; ++mo) {
                const int swz = (mo * 16 + lg * 4) ^ ((l15 & 7) << 2);
                *reinterpret_cast<f32x4*>(lbase + jrow * 64 + swz) = acc[mo][n];
            }
        }

        // epilogue B: finalize (+adj*W64 +bias) + 1 KB ascending stores
#pragma unroll
        for (int t = 0; t < 8; ++t) {
            const int jr = t * 4 + lg;
            const int oo = l15 * 4;
            f32x4 v = *reinterpret_cast<const f32x4*>(
                lbase + jr * 64 + (oo ^ ((jr & 7) << 2)));
            const float av = arow[jt + jr];
#pragma unroll
            for (int r = 0; r < 4; ++r)
                v[r] = v[r] + av * wlB[r] + bvB[r];
            float* op = out + ((size_t)i * N_NODES + jt + jr) * NOUT + oo;
            *reinterpret_cast<f32x4*>(op) = v;
        }
    };

    // ---- j loop: 12 tiles, fj loads pipelined one tile ahead ----
    bf16x8 fjA[2][2], fjB[2][2];
    load_fj(fjA, 0);
#pragma unroll 1
    for (int it = 0; it < 12; it += 2) {
        load_fj(fjB, it + 1);           // issue next-tile loads early
        tile(fjA, it);
        if (it + 2 < 12) load_fj(fjA, it + 2);
        tile(fjB, it + 1);
    }
}

extern "C" void kernel_launch(void* const* d_in, const int* in_sizes, int n_in,
                              void* d_out, int out_size, void* d_ws, size_t ws_size,
                              hipStream_t stream) {
    const float* feat = (const float*)d_in[0];   // [1536][64]
    const float* adj  = (const float*)d_in[1];   // [1536][1536]
    const float* W    = (const float*)d_in[2];   // [64][65]
    const float* b    = (const float*)d_in[3];   // [64]
    float* out = (float*)d_out;                  // [1536*1536][64]

    dim3 grid(N_NODES);
    dim3 block(256);
    edge_gcn_mfma<<<grid, block, 0, stream>>>(feat, adj, W, b, out);
}

// Round 17
// 127.365 us; speedup vs baseline: 1.1193x; 1.1193x over previous
//
#include <hip/hip_runtime.h>
#include <hip/hip_bf16.h>

#define N_NODES 1536
#define NF 64
#define NOUT 64
#define FIN 65
#define TIB 12          // i-rows per block
#define TIW 3           // i-rows per wave

typedef __bf16 bf16x8 __attribute__((ext_vector_type(8)));
typedef float f32x4 __attribute__((ext_vector_type(4)));

// One block: 12 i-rows x 128 j-cols; wave wv owns i in [i0+wv*3, i0+wv*3+3)
// and sweeps ALL 128 j per i. Swapped-operand MFMA
//   D[o][j] = sum_k W[o][k] * |feat[j][k]-feat[i][k]|
// DRAM-locality experiment, clean version of R16: per-wave store stream is
// 32 KB strictly-ascending contiguous per i (4x longer runs than R11's 8 KB,
// 2048 vs 3072 machine-wide write cursors) while the loop body stays DS-only
// (R11's property): the block's 128-j feat window is staged in LDS as bf16
// (16 KB, XOR-swizzled so the 16-lane fragment reads at 128 B row stride are
// ~conflict-free), so in-loop fj reads are lgkmcnt ds_reads, never vmcnt.
// All other global reads hoisted to setup (fslab/aslab/W/bias). Epilogue
// transposes each wave's 32j x 64o sub-tile through wave-private XOR-swizzled
// LDS so stores are 1 KB lane-contiguous full lines.
// LDS: 32 (transpose) + 16 (fjslab) + 1.5 (fslab) + 6 (aslab) = 55.5 KB;
// x2 blocks/CU = 111 KB. Grid 12 x 128 = 1536 = exactly 3 rounds at 2/CU.
__global__ __launch_bounds__(256, 2)
void edge_gcn_mfma(const float* __restrict__ feat,
                   const float* __restrict__ adj,
                   const float* __restrict__ W,
                   const float* __restrict__ b,
                   float* __restrict__ out)
{
    const int tid  = threadIdx.x;
    const int lane = tid & 63;
    const int wv   = tid >> 6;          // wave 0..3
    const int l15  = lane & 15;
    const int lg   = lane >> 4;         // 0..3

    const int i0 = blockIdx.y * TIB;
    const int j0 = blockIdx.x * 128;
    const int iw = i0 + wv * TIW;       // wave's first i-row

    __shared__ float  lds[8192];        // 4 waves x 8 KB transpose buffers
    __shared__ __bf16 fjslab[128 * NF]; // 128-j feat window, bf16, swizzled
    __shared__ __bf16 fslab[TIB * NF];  // 12-i feat slab, bf16 (1.5 KB)
    __shared__ float  aslab[TIB * 128]; // 12 x 128 adj tile (6 KB)
    float* const lbase = lds + wv * 2048;

    // ---- setup: fjslab = feat[j0..j0+128) as bf16, slot-swizzled ----
    // row r (0..127), 16B slot s (0..7): data = feat[j0+r][s*8..s*8+8],
    // stored at slot s^(r&7)  (involution; read applies the same XOR).
#pragma unroll
    for (int h = 0; h < 4; ++h) {
        const int idx = h * 256 + tid;       // 0..1023 = 128 rows x 8 slots
        const int r = idx >> 3, s = idx & 7;
        const float* fp = feat + (size_t)(j0 + r) * NF + s * 8;
        f32x4 lo = *reinterpret_cast<const f32x4*>(fp);
        f32x4 hi = *reinterpret_cast<const f32x4*>(fp + 4);
        bf16x8 v;
#pragma unroll
        for (int e = 0; e < 4; ++e) { v[e] = (__bf16)lo[e]; v[e+4] = (__bf16)hi[e]; }
        *reinterpret_cast<bf16x8*>(&fjslab[r * NF + ((s ^ (r & 7)) * 8)]) = v;
    }
    // ---- setup: fslab = feat[i0..i0+12) as bf16 (broadcast reads later) ----
    if (tid < 96) {
        const int r = tid >> 3, s = tid & 7;
        const float* fp = feat + (size_t)(i0 + r) * NF + s * 8;
        f32x4 lo = *reinterpret_cast<const f32x4*>(fp);
        f32x4 hi = *reinterpret_cast<const f32x4*>(fp + 4);
        bf16x8 v;
#pragma unroll
        for (int e = 0; e < 4; ++e) { v[e] = (__bf16)lo[e]; v[e+4] = (__bf16)hi[e]; }
        *reinterpret_cast<bf16x8*>(&fslab[r * NF + s * 8]) = v;
    }
    // ---- setup: aslab = adj[i0..i0+12)[j0..j0+128) ----
#pragma unroll
    for (int h = 0; h < 2; ++h) {
        const int idx = h * 256 + tid;       // 0..511, need 384
        if (idx < 384) {
            const int row = idx >> 5, col = (idx & 31) * 4;
            *reinterpret_cast<f32x4*>(&aslab[row * 128 + col]) =
                *reinterpret_cast<const f32x4*>(
                    &adj[(size_t)(i0 + row) * N_NODES + j0 + col]);
        }
    }

    // ---- A fragments (W): once ----
    bf16x8 afrag[2][4];                 // [kk][mo]
#pragma unroll
    for (int kk = 0; kk < 2; ++kk)
#pragma unroll
        for (int mo = 0; mo < 4; ++mo) {
            const float* wp = W + (mo * 16 + l15) * FIN + kk * 32 + lg * 8;
#pragma unroll
            for (int e = 0; e < 8; ++e) afrag[kk][mo][e] = (__bf16)wp[e];
        }

    // ---- epilogue-B constants: o = l15*4 + r ----
    float wlB[4], bvB[4];
#pragma unroll
    for (int r = 0; r < 4; ++r) {
        wlB[r] = W[(l15 * 4 + r) * FIN + NF];
        bvB[r] = b[l15 * 4 + r];
    }

    __syncthreads();                    // slabs ready; only barrier

    // ---- i loop: 3 i's/wave; j sweep: 4 sub-tiles of 32 j, ascending ----
#pragma unroll 1
    for (int ii = 0; ii < TIW; ++ii) {
        const int i = iw + ii;

        bf16x8 fib[2];                  // broadcast ds_read from fslab
#pragma unroll
        for (int kk = 0; kk < 2; ++kk)
            fib[kk] = *reinterpret_cast<const bf16x8*>(
                &fslab[(wv * TIW + ii) * NF + kk * 32 + lg * 8]);

#pragma unroll 1
        for (int t = 0; t < 4; ++t) {
            // fj fragments from fjslab (same XOR as setup)
            bf16x8 fj[2][2];            // [n][kk]
#pragma unroll
            for (int n = 0; n < 2; ++n)
#pragma unroll
                for (int kk = 0; kk < 2; ++kk) {
                    const int row  = t * 32 + n * 16 + l15;
                    const int slot = (kk * 4 + lg) ^ (row & 7);
                    fj[n][kk] = *reinterpret_cast<const bf16x8*>(
                        &fjslab[row * NF + slot * 8]);
                }

            f32x4 acc[4][2];            // [mo][n]
#pragma unroll
            for (int mo = 0; mo < 4; ++mo)
#pragma unroll
                for (int n = 0; n < 2; ++n)
                    acc[mo][n] = (f32x4){0.f, 0.f, 0.f, 0.f};

#pragma unroll
            for (int n = 0; n < 2; ++n)
#pragma unroll
                for (int kk = 0; kk < 2; ++kk) {
                    bf16x8 bfrag;
#pragma unroll
                    for (int e = 0; e < 8; ++e)
                        bfrag[e] = (__bf16)fabsf((float)fj[n][kk][e] -
                                                 (float)fib[kk][e]);
#pragma unroll
                    for (int mo = 0; mo < 4; ++mo)
                        acc[mo][n] = __builtin_amdgcn_mfma_f32_16x16x32_bf16(
                            afrag[kk][mo], bfrag, acc[mo][n], 0, 0, 0);
                }

            // epilogue A: raw acc -> transposed LDS tile
            // T[j(32)][o(64)], off = j*64 + (o ^ ((j&7)<<2))
#pragma unroll
            for (int n = 0; n < 2; ++n) {
                const int jrow = n * 16 + l15;
#pragma unroll
                for (int mo = 0; mo < 4; ++mo) {
                    const int swz = (mo * 16 + lg * 4) ^ ((l15 & 7) << 2);
                    *reinterpret_cast<f32x4*>(lbase + jrow * 64 + swz) =
                        acc[mo][n];
                }
            }

            // epilogue B: finalize (+adj*W64 +bias) + 1 KB ascending stores
#pragma unroll
            for (int tt = 0; tt < 8; ++tt) {
                const int jr = tt * 4 + lg;
                const int oo = l15 * 4;
                f32x4 v = *reinterpret_cast<const f32x4*>(
                    lbase + jr * 64 + (oo ^ ((jr & 7) << 2)));
                const float av = aslab[(wv * TIW + ii) * 128 + t * 32 + jr];
#pragma unroll
                for (int r = 0; r < 4; ++r)
                    v[r] = v[r] + av * wlB[r] + bvB[r];
                float* op = out +
                    ((size_t)i * N_NODES + j0 + t * 32 + jr) * NOUT + oo;
                *reinterpret_cast<f32x4*>(op) = v;
            }
        }
    }
}

extern "C" void kernel_launch(void* const* d_in, const int* in_sizes, int n_in,
                              void* d_out, int out_size, void* d_ws, size_t ws_size,
                              hipStream_t stream) {
    const float* feat = (const float*)d_in[0];   // [1536][64]
    const float* adj  = (const float*)d_in[1];   // [1536][1536]
    const float* W    = (const float*)d_in[2];   // [64][65]
    const float* b    = (const float*)d_in[3];   // [64]
    float* out = (float*)d_out;                  // [1536*1536][64]

    dim3 grid(N_NODES / 128, N_NODES / TIB);
    dim3 block(256);
    edge_gcn_mfma<<<grid, block, 0, stream>>>(feat, adj, W, b, out);
}

// Round 18
// 122.851 us; speedup vs baseline: 1.1605x; 1.0367x over previous
//
#include <hip/hip_runtime.h>
#include <hip/hip_bf16.h>

#define N_NODES 1536
#define NF 64
#define NOUT 64
#define FIN 65
#define TI 24

typedef __bf16 bf16x8 __attribute__((ext_vector_type(8)));
typedef float f32x4 __attribute__((ext_vector_type(4)));

// FINAL (empirically-best, = R11 @ 122.2 us): TI=24 i-rows x 128 j-cols.
// Swapped-operand MFMA:  D[o][j] = sum_k W[o][k] * |feat[j][k]-feat[i][k]|
// ONE dispatch round: 768 blocks = exactly 3/CU (launch_bounds(256,3)).
// All global reads hoisted to kernel start (adj 12KB + feat 6KB slabs, W,
// bias); after the single barrier the i-loop body is DS ops + stores only
// (no vmcnt-load can force a store drain). Epilogue transposes each wave's
// 32j x 64o tile through wave-private XOR-swizzled LDS so global stores
// are 1 KB lane-contiguous full lines (kills write-allocate RMW traffic).
// LDS: 32 + 6 + 12 = 50 KB; x3 blocks = 150 KB/CU.
//
// Ceiling evidence (R2-R17): store shape, occupancy (2/3/4 blk/CU), reg
// store-deferral, nt stores, phase stagger, producer-consumer waves, and
// DRAM-contiguous write cursors all land 122-132 us -> the ~5 TB/s
// effective rate for this mixed read+compute+write pattern is the
// machine-side plateau; 604 MB output at that rate + setup = ~122 us.
__global__ __launch_bounds__(256, 3)
void edge_gcn_mfma(const float* __restrict__ feat,
                   const float* __restrict__ adj,
                   const float* __restrict__ W,
                   const float* __restrict__ b,
                   float* __restrict__ out)
{
    const int tid  = threadIdx.x;
    const int lane = tid & 63;
    const int wv   = tid >> 6;          // wave 0..3
    const int l15  = lane & 15;
    const int lg   = lane >> 4;         // 0..3

    const int i0 = blockIdx.y * TI;
    const int j0 = blockIdx.x * 128;
    const int jw = j0 + wv * 32;        // this wave's 32 j's

    __shared__ float lds[8192];         // 4 waves x 8 KB transpose buffers
    __shared__ float fslab[TI * NF];    // 24 x 64 feat i-slab (6 KB)
    __shared__ float aslab[TI * 128];   // 24 x 128 adj tile (12 KB)
    float* const lbase = lds + wv * 2048;

    // ---- cooperative feat i-slab load: 24 rows x 64 f32 = 384 f32x4 ----
#pragma unroll
    for (int h = 0; h < 2; ++h) {
        const int idx = h * 256 + tid;       // 0..511, need 384
        if (idx < 384) {
            const int row = idx >> 4;        // 0..23
            const int col = (idx & 15) * 4;  // 0..60
            *reinterpret_cast<f32x4*>(&fslab[row * NF + col]) =
                *reinterpret_cast<const f32x4*>(
                    &feat[(size_t)(i0 + row) * NF + col]);
        }
    }
    // ---- cooperative adj tile load: 24 rows x 128 f32 = 768 f32x4 ----
#pragma unroll
    for (int h = 0; h < 3; ++h) {
        const int idx = h * 256 + tid;       // 0..767
        const int row = idx >> 5;            // 0..23
        const int col = (idx & 31) * 4;      // 0..124
        *reinterpret_cast<f32x4*>(&aslab[row * 128 + col]) =
            *reinterpret_cast<const f32x4*>(
                &adj[(size_t)(i0 + row) * N_NODES + j0 + col]);
    }

    // ---- A fragments (W): once per block ----
    bf16x8 afrag[2][4];                 // [kk][mo]
#pragma unroll
    for (int kk = 0; kk < 2; ++kk) {
#pragma unroll
        for (int mo = 0; mo < 4; ++mo) {
            const float* wp = W + (mo * 16 + l15) * FIN + kk * 32 + lg * 8;
#pragma unroll
            for (int e = 0; e < 8; ++e) afrag[kk][mo][e] = (__bf16)wp[e];
        }
    }

    // ---- feat[j] fragments: once per block ----
    float fjr[2][2][8];                 // [n][kk][e]
#pragma unroll
    for (int n = 0; n < 2; ++n) {
        const float* fjrow = feat + (jw + n * 16 + l15) * NF;
#pragma unroll
        for (int kk = 0; kk < 2; ++kk)
#pragma unroll
            for (int e = 0; e < 8; ++e)
                fjr[n][kk][e] = fjrow[kk * 32 + lg * 8 + e];
    }

    // ---- epilogue-B constants: o = l15*4 + r ----
    float wlB[4], bvB[4];
#pragma unroll
    for (int r = 0; r < 4; ++r) {
        wlB[r] = W[(l15 * 4 + r) * FIN + NF];
        bvB[r] = b[l15 * 4 + r];
    }

    __syncthreads();                    // slabs ready; only barrier

    // ---- i loop (rolled: low VGPR; body has NO global loads) ----
#pragma unroll 1
    for (int ii = 0; ii < TI; ++ii) {
        const int i = i0 + ii;

        float fi[2][8];                 // from LDS (broadcast, conflict-free)
#pragma unroll
        for (int kk = 0; kk < 2; ++kk) {
            const float* fp = &fslab[ii * NF + kk * 32 + lg * 8];
#pragma unroll
            for (int e = 0; e < 8; ++e) fi[kk][e] = fp[e];
        }

        f32x4 acc[4][2];                // [mo][n]
#pragma unroll
        for (int mo = 0; mo < 4; ++mo)
#pragma unroll
            for (int n = 0; n < 2; ++n)
                acc[mo][n] = (f32x4){0.f, 0.f, 0.f, 0.f};

#pragma unroll
        for (int n = 0; n < 2; ++n) {
#pragma unroll
            for (int kk = 0; kk < 2; ++kk) {
                bf16x8 bfrag;
#pragma unroll
                for (int e = 0; e < 8; ++e)
                    bfrag[e] = (__bf16)fabsf(fjr[n][kk][e] - fi[kk][e]);
#pragma unroll
                for (int mo = 0; mo < 4; ++mo)
                    acc[mo][n] = __builtin_amdgcn_mfma_f32_16x16x32_bf16(
                        afrag[kk][mo], bfrag, acc[mo][n], 0, 0, 0);
            }
        }

        // ---- epilogue A: raw acc -> transposed LDS tile ----
        // tile T[j(32)][o(64)], float off = j*64 + (o ^ ((j&7)<<2))
#pragma unroll
        for (int n = 0; n < 2; ++n) {
            const int jrow = n * 16 + l15;
#pragma unroll
            for (int mo = 0; mo < 4; ++mo) {
                const int swz = (mo * 16 + lg * 4) ^ ((l15 & 7) << 2);
                *reinterpret_cast<f32x4*>(lbase + jrow * 64 + swz) = acc[mo][n];
            }
        }

        // ---- epilogue B: finalize (+adj*W64 +bias) + 1 KB stores ----
#pragma unroll
        for (int t = 0; t < 8; ++t) {
            const int jr = t * 4 + lg;
            const int oo = l15 * 4;
            f32x4 v = *reinterpret_cast<const f32x4*>(
                lbase + jr * 64 + (oo ^ ((jr & 7) << 2)));
            const float av = aslab[ii * 128 + wv * 32 + jr];
#pragma unroll
            for (int r = 0; r < 4; ++r)
                v[r] = v[r] + av * wlB[r] + bvB[r];
            float* op = out + ((size_t)i * N_NODES + jw + jr) * NOUT + oo;
            *reinterpret_cast<f32x4*>(op) = v;
        }
    }
}

extern "C" void kernel_launch(void* const* d_in, const int* in_sizes, int n_in,
                              void* d_out, int out_size, void* d_ws, size_t ws_size,
                              hipStream_t stream) {
    const float* feat = (const float*)d_in[0];   // [1536][64]
    const float* adj  = (const float*)d_in[1];   // [1536][1536]
    const float* W    = (const float*)d_in[2];   // [64][65]
    const float* b    = (const float*)d_in[3];   // [64]
    float* out = (float*)d_out;                  // [1536*1536][64]

    dim3 grid(N_NODES / 128, N_NODES / TI);
    dim3 block(256);
    edge_gcn_mfma<<<grid, block, 0, stream>>>(feat, adj, W, b, out);
}